// Round 3
// baseline (893.419 us; speedup 1.0000x reference)
//
#include <hip/hip_runtime.h>
#include <hip/hip_bf16.h>

#define FRAMES 512
#define BATCH 2048
#define IN_DIM 84
#define HIDDEN 300
#define OUT_DIM 10

#define MT 16            // batch rows per workgroup
#define NT 5             // N-tiles per wave (4 waves x 5 = 20 tiles = 320 cols, tile 19 all-zero)
#define KFT 13           // K-fragments: 10 for h (320), 3 for x (96)
#define XREG 5120        // short offset of x region within a buffer
#define XSTR 104         // x row stride in shorts (208 B -> 2-way banks, free)
#define BUFS 8192        // shorts per buffer (16 KiB)

typedef short s4v __attribute__((ext_vector_type(4)));
typedef short s8v __attribute__((ext_vector_type(8)));
typedef float f4v __attribute__((ext_vector_type(4)));

__device__ __forceinline__ short f2b(float x) {
    __hip_bfloat16 h = __float2bfloat16(x);
    return *reinterpret_cast<short*>(&h);
}
__device__ __forceinline__ float b2f(short s) {
    __hip_bfloat16 h = *reinterpret_cast<__hip_bfloat16*>(&s);
    return __bfloat162float(h);
}
__device__ __forceinline__ float fast_tanh(float z) {
    float ex = __builtin_amdgcn_exp2f(z * 2.88539008177792681f); // exp(2z)
    return fmaf(-2.f, __builtin_amdgcn_rcpf(ex + 1.f), 1.f);
}

// h region layout (per buffer): short index of (k,row) = (k>>2)*64 + (k&3)*16 + row.
// Each 64-short (128 B) window = one k-group (4 k) x 16 rows = a 4x16 matrix.
// tr_b64 read with per-lane addr = window_base + (lane&15)*8 delivers lane r the
// column r = A[row=r][k..k+3]. Writes: (col fixed, 4 consecutive rows) = 1 b64.

#define TRH(KF, S0, S1) do { s4v lo_, hi_; \
    asm volatile("ds_read_b64_tr_b16 %0, %2 offset:" S0 "\n\t" \
                 "ds_read_b64_tr_b16 %1, %2 offset:" S1 \
                 : "=v"(lo_), "=v"(hi_) : "v"(ra)); \
    af[KF] = __builtin_shufflevector(lo_, hi_, 0, 1, 2, 3, 4, 5, 6, 7); } while (0)

__global__ __launch_bounds__(256, 1)
void rnn_kernel(const float* __restrict__ x, const float* __restrict__ h0,
                const float* __restrict__ Wi, const float* __restrict__ Wh,
                const float* __restrict__ Wo, float* __restrict__ out)
{
    __shared__ short lds[2 * BUFS];
    const int tid  = threadIdx.x;
    const int lane = tid & 63;
    const int wv   = tid >> 6;          // wave 0..3
    const int lrow = lane & 15;
    const int lkhi = lane >> 4;
    const int b0   = blockIdx.x * MT;

    // ---- weight-stationary B fragments (VGPR+AGPR unified file) ----
    s8v w[NT][KFT];
#pragma unroll
    for (int i = 0; i < NT; ++i) {
        const int n = (wv * NT + i) * 16 + lrow;
#pragma unroll
        for (int kf = 0; kf < 10; ++kf) {
            s8v v;
#pragma unroll
            for (int j = 0; j < 8; ++j) {
                int k = kf * 32 + lkhi * 8 + j;
                float f = (n < HIDDEN && k < HIDDEN) ? Wh[n * HIDDEN + k] : 0.f;
                v[j] = f2b(f);
            }
            w[i][kf] = v;
        }
#pragma unroll
        for (int kf = 10; kf < 13; ++kf) {
            s8v v;
#pragma unroll
            for (int j = 0; j < 8; ++j) {
                int k = (kf - 10) * 32 + lkhi * 8 + j;
                float f = (n < HIDDEN && k < IN_DIM) ? Wi[n * IN_DIM + k] : 0.f;
                v[j] = f2b(f);
            }
            w[i][kf] = v;
        }
    }

    // ---- zero both buffers (covers padding: k 300..319 of h, cols 84..103 of x) ----
    for (int i = tid; i < 2 * BUFS / 4; i += 256)
        ((s4v*)lds)[i] = (s4v){0, 0, 0, 0};
    __syncthreads();

    // ---- h0 -> buf0 transposed h region ----
    for (int i = tid; i < MT * HIDDEN; i += 256) {
        int r = i / HIDDEN, k = i % HIDDEN;
        lds[(k >> 2) * 64 + (k & 3) * 16 + r] = f2b(h0[(size_t)(b0 + r) * HIDDEN + k]);
    }
    // ---- frame 0 x -> buf0 x region (336 float4) ----
    {
        const float4* xs = reinterpret_cast<const float4*>(x + (size_t)b0 * IN_DIM);
        float4 v = xs[tid];
        int r = tid / 21, c4 = (tid % 21) * 4;
        s4v pk = {f2b(v.x), f2b(v.y), f2b(v.z), f2b(v.w)};
        *(s4v*)&lds[XREG + r * XSTR + c4] = pk;
        if (tid < 80) {
            float4 v1 = xs[256 + tid];
            int vi = 256 + tid; r = vi / 21; c4 = (vi % 21) * 4;
            s4v p1 = {f2b(v1.x), f2b(v1.y), f2b(v1.z), f2b(v1.w)};
            *(s4v*)&lds[XREG + r * XSTR + c4] = p1;
        }
    }
    __syncthreads();

    // ---- per-lane bases ----
    const unsigned rdA0 = (unsigned)(size_t)(&lds[0]) + (unsigned)(lkhi * 256 + lrow * 8);
    int wb  = BUFS + wv * (NT * 256) + (lrow >> 2) * 64 + (lrow & 3) * 16 + lkhi * 4; // h' -> buf1
    int xrd = XREG + lrow * XSTR + lkhi * 8;                                          // x  <- buf0
    int xwb = BUFS + XREG;                                                            // x  -> buf1
    const int xr1 = tid / 21,         xc1 = (tid % 21) * 4;
    const int xr2 = (256 + tid) / 21, xc2 = ((256 + tid) % 21) * 4;

    for (int s = 0; s < FRAMES; ++s) {
        // prefetch next frame's x (HBM latency hides under MFMA/tanh)
        float4 xv0, xv1;
        const bool pf = (s + 1 < FRAMES);
        if (pf) {
            const float4* xs = reinterpret_cast<const float4*>(
                x + ((size_t)(s + 1) * BATCH + b0) * IN_DIM);
            xv0 = xs[tid];
            if (tid < 80) xv1 = xs[256 + tid];
        }

        // A fragments: h via hardware transpose reads, x via b128 row-major reads
        const unsigned ra = rdA0 + (unsigned)((s & 1) << 14);
        s8v af[KFT];
        TRH(0, "0",    "128");  TRH(1, "1024", "1152"); TRH(2, "2048", "2176");
        TRH(3, "3072", "3200"); TRH(4, "4096", "4224"); TRH(5, "5120", "5248");
        TRH(6, "6144", "6272"); TRH(7, "7168", "7296"); TRH(8, "8192", "8320");
        TRH(9, "9216", "9344");
        af[10] = *(const s8v*)&lds[xrd];
        af[11] = *(const s8v*)&lds[xrd + 32];
        af[12] = *(const s8v*)&lds[xrd + 64];

        asm volatile("s_waitcnt lgkmcnt(0)" ::: "memory");   // rule #18
        __builtin_amdgcn_sched_barrier(0);

        f4v acc[NT];
#pragma unroll
        for (int i = 0; i < NT; ++i) acc[i] = (f4v){0.f, 0.f, 0.f, 0.f};
#pragma unroll
        for (int kf = 0; kf < KFT; ++kf)
#pragma unroll
            for (int i = 0; i < NT; ++i)
                acc[i] = __builtin_amdgcn_mfma_f32_16x16x32_bf16(af[kf], w[i][kf], acc[i], 0, 0, 0);

        // tanh + one b64 transposed write per tile (4 rows, fixed col per lane)
#pragma unroll
        for (int i = 0; i < NT; ++i) {
            s4v hv;
#pragma unroll
            for (int r = 0; r < 4; ++r) hv[r] = f2b(fast_tanh(acc[i][r]));
            *(s4v*)&lds[wb + i * 256] = hv;
        }

        // commit prefetched x
        if (pf) {
            s4v pk = {f2b(xv0.x), f2b(xv0.y), f2b(xv0.z), f2b(xv0.w)};
            *(s4v*)&lds[xwb + xr1 * XSTR + xc1] = pk;
            if (tid < 80) {
                s4v p1 = {f2b(xv1.x), f2b(xv1.y), f2b(xv1.z), f2b(xv1.w)};
                *(s4v*)&lds[xwb + xr2 * XSTR + xc2] = p1;
            }
        }
        __syncthreads();
        wb ^= BUFS; xrd ^= BUFS; xwb ^= BUFS;
    }

    // ---- epilogue: final h in buf0 (FRAMES even) ----
    float* hout = out + BATCH * OUT_DIM;
    for (int i = tid; i < MT * HIDDEN; i += 256) {
        int r = i / HIDDEN, k = i % HIDDEN;
        hout[(size_t)(b0 + r) * HIDDEN + k] = b2f(lds[(k >> 2) * 64 + (k & 3) * 16 + r]);
    }
    if (tid < MT * OUT_DIM) {
        int r = tid / OUT_DIM, c = tid % OUT_DIM;
        float sum = 0.f;
        for (int k = 0; k < HIDDEN; ++k)
            sum = fmaf(b2f(lds[(k >> 2) * 64 + (k & 3) * 16 + r]), Wo[c * HIDDEN + k], sum);
        out[(b0 + r) * OUT_DIM + c] = sum;
    }
}

extern "C" void kernel_launch(void* const* d_in, const int* in_sizes, int n_in,
                              void* d_out, int out_size, void* d_ws, size_t ws_size,
                              hipStream_t stream) {
    const float* x  = (const float*)d_in[0];
    const float* h0 = (const float*)d_in[1];
    const float* Wi = (const float*)d_in[2];
    const float* Wh = (const float*)d_in[3];
    const float* Wo = (const float*)d_in[4];
    float* out = (float*)d_out;
    rnn_kernel<<<dim3(BATCH / MT), dim3(256), 0, stream>>>(x, h0, Wi, Wh, Wo, out);
}

// Round 5
// 847.649 us; speedup vs baseline: 1.0540x; 1.0540x over previous
//
#include <hip/hip_runtime.h>
#include <hip/hip_bf16.h>

#define FRAMES 512
#define BATCH 2048
#define IN_DIM 84
#define HIDDEN 300
#define OUT_DIM 10

#define MT 16          // batch rows per workgroup
#define KH 320         // padded hidden K (h region cols 0..319)
#define KA 416         // A-buffer cols per row (shorts): 320 h + 96 x
#define NT_MAX 3       // max N-tiles per wave (8 waves, tiles 0..18 round-robin)

typedef __attribute__((ext_vector_type(8))) short s8v;
typedef __attribute__((ext_vector_type(4))) short s4v;
typedef __attribute__((ext_vector_type(4))) float f4v;

__device__ __forceinline__ short f2b(float x) {
    __hip_bfloat16 h = __float2bfloat16(x);
    return *reinterpret_cast<short*>(&h);
}
__device__ __forceinline__ float b2f(short s) {
    __hip_bfloat16 h = *reinterpret_cast<__hip_bfloat16*>(&s);
    return __bfloat162float(h);
}
__device__ __forceinline__ float fast_tanh(float z) {
    // tanh(z) = 1 - 2/(exp(2z)+1); exp2 overflow gives exact +/-1 limits
    float ex = __builtin_amdgcn_exp2f(z * 2.88539008177792681f); // exp(2z)
    return fmaf(-2.f, __builtin_amdgcn_rcpf(ex + 1.f), 1.f);
}

// Swapped-operand step:  D[n][b] = sum_k W[n][k] * h[b][k]
//   A-operand = weight tile  (lane l: n = t*16 + (l&15), k = (l>>4)*8 + j) - registers
//   B-operand = h fragment   (lane l: b = l&15,          k = (l>>4)*8 + j) - LDS b128
//   C/D       = lane l: batch = l&15, n_local = (l>>4)*4 + r  -> 4 consecutive
//               hidden cols per lane => ONE ds_write_b64 per tile, row-major.
// NOTE: XOR swizzle must be applied to the FULL index (swizzle bits 3..5
// alias the n-offset bits >=4 under addition-with-carry).

__global__ __launch_bounds__(512, 2)
void rnn_kernel(const float* __restrict__ x, const float* __restrict__ h0,
                const float* __restrict__ Wi, const float* __restrict__ Wh,
                const float* __restrict__ Wo, float* __restrict__ out)
{
    __shared__ short abuf[2][MT * KA];   // ping-pong h|x buffer (bf16, row-major swizzled)
    const int tid  = threadIdx.x;
    const int lane = tid & 63;
    const int wv   = tid >> 6;          // wave 0..7
    const int l15  = lane & 15;
    const int lkhi = lane >> 4;         // k-subchunk 0..3 (and n_local quad for C)
    const int b0   = blockIdx.x * MT;
    const int my_nt = (wv < 3) ? 3 : 2; // tiles t = wv, wv+8, wv+16 (<19)

    // ---- weight-stationary A-operand fragments (W rows = n) ----
    s8v w[NT_MAX][13];
#pragma unroll
    for (int i = 0; i < NT_MAX; ++i) {
        if (i < my_nt) {
            const int n = (wv + 8 * i) * 16 + l15;
#pragma unroll
            for (int kf = 0; kf < 10; ++kf) {          // recurrent part: Wh[n][k]
                s8v v;
#pragma unroll
                for (int j = 0; j < 8; ++j) {
                    int k = kf * 32 + lkhi * 8 + j;
                    float f = (n < HIDDEN && k < HIDDEN) ? Wh[n * HIDDEN + k] : 0.f;
                    v[j] = f2b(f);
                }
                w[i][kf] = v;
            }
#pragma unroll
            for (int kf = 10; kf < 13; ++kf) {         // input part: Wi[n][k]
                s8v v;
#pragma unroll
                for (int j = 0; j < 8; ++j) {
                    int k = (kf - 10) * 32 + lkhi * 8 + j;
                    float f = (n < HIDDEN && k < IN_DIM) ? Wi[n * IN_DIM + k] : 0.f;
                    v[j] = f2b(f);
                }
                w[i][kf] = v;
            }
        }
    }

    // ---- zero both LDS buffers (covers all pad regions) ----
    {
        s4v z = (s4v){0, 0, 0, 0};
        for (int i = tid; i < 2 * MT * KA / 4; i += 512)
            ((s4v*)abuf)[i] = z;
    }
    __syncthreads();

    // ---- initial hidden state -> buf0 h-region (bf16, swizzled row-major) ----
    for (int i = tid; i < MT * HIDDEN; i += 512) {
        int r = i / HIDDEN, c = i % HIDDEN;
        int sidx = (r * KA + c) ^ ((r & 7) << 3);
        abuf[0][sidx] = f2b(h0[(size_t)(b0 + r) * HIDDEN + c]);
    }
    // ---- frame 0 x -> buf0 x-region (336 float4 = 16 rows x 84 f32) ----
    if (tid < 336) {
        const float4* xs = reinterpret_cast<const float4*>(x + (size_t)b0 * IN_DIM);
        float4 v0 = xs[tid];
        int r = tid / 21, c4 = (tid % 21) * 4;
        int sidx = (r * KA + KH + c4) ^ ((r & 7) << 3);
        s4v pk = {f2b(v0.x), f2b(v0.y), f2b(v0.z), f2b(v0.w)};
        *reinterpret_cast<s4v*>(&abuf[0][sidx]) = pk;
    }
    __syncthreads();

    // ---- per-lane constants ----
    const int rbase = l15 * KA;                     // B-frag read base (batch row)
    const int rxor  = (l15 & 7) << 3;
    const int wrow  = l15 * KA + lkhi * 4;          // h' write base BEFORE n-tile offset + XOR
    const int xr    = tid / 21, xc4 = (tid % 21) * 4;
    const int xsidx = (xr * KA + KH + xc4) ^ ((xr & 7) << 3);

    for (int s = 0; s < FRAMES; ++s) {
        const short* abp = abuf[s & 1];
        short* abn = abuf[(s & 1) ^ 1];

        // prefetch next frame's x into registers (HBM latency hides under MFMA)
        float4 xv0;
        const bool pf = (s + 1 < FRAMES) && (tid < 336);
        if (pf) {
            const float4* xs = reinterpret_cast<const float4*>(
                x + ((size_t)(s + 1) * BATCH + b0) * IN_DIM);
            xv0 = xs[tid];
        }

        // B-fragments (h rows): 13 x ds_read_b128, compiler-scheduled lgkmcnt
        s8v bf[13];
#pragma unroll
        for (int kf = 0; kf < 13; ++kf) {
            int sidx = (rbase + kf * 32 + lkhi * 8) ^ rxor;
            bf[kf] = *reinterpret_cast<const s8v*>(&abp[sidx]);
        }

        f4v acc[NT_MAX];
#pragma unroll
        for (int i = 0; i < NT_MAX; ++i) acc[i] = (f4v){0.f, 0.f, 0.f, 0.f};

#pragma unroll
        for (int kf = 0; kf < 13; ++kf) {
#pragma unroll
            for (int i = 0; i < NT_MAX; ++i)
                if (i < my_nt)
                    acc[i] = __builtin_amdgcn_mfma_f32_16x16x32_bf16(w[i][kf], bf[kf], acc[i], 0, 0, 0);
        }

        // tanh + ONE packed b64 write per tile: h'[batch=l15][n0..n0+3]
#pragma unroll
        for (int i = 0; i < NT_MAX; ++i) {
            if (i < my_nt) {
                s4v hv;
#pragma unroll
                for (int r = 0; r < 4; ++r) hv[r] = f2b(fast_tanh(acc[i][r]));
                int sidx = (wrow + (wv + 8 * i) * 16) ^ rxor;   // full index, THEN xor
                *reinterpret_cast<s4v*>(&abn[sidx]) = hv;
            }
        }

        // commit prefetched x into next buffer's x-region
        if (pf) {
            s4v pk = {f2b(xv0.x), f2b(xv0.y), f2b(xv0.z), f2b(xv0.w)};
            *reinterpret_cast<s4v*>(&abn[xsidx]) = pk;
        }
        __syncthreads();
    }

    // ---- epilogue: h_final sits in abuf[0] (FRAMES even) ----
    float* hout = out + BATCH * OUT_DIM;
    for (int i = tid; i < MT * HIDDEN; i += 512) {
        int r = i / HIDDEN, c = i % HIDDEN;
        int sidx = (r * KA + c) ^ ((r & 7) << 3);
        hout[(size_t)(b0 + r) * HIDDEN + c] = b2f(abuf[0][sidx]);
    }
    // out = h_final @ Wo^T  (tiny: 16x10 per WG, VALU)
    if (tid < MT * OUT_DIM) {
        int r = tid / OUT_DIM, c = tid % OUT_DIM;
        float sum = 0.f;
        for (int k = 0; k < HIDDEN; ++k) {
            int sidx = (r * KA + k) ^ ((r & 7) << 3);
            sum = fmaf(b2f(abuf[0][sidx]), Wo[c * HIDDEN + k], sum);
        }
        out[(b0 + r) * OUT_DIM + c] = sum;
    }
}

extern "C" void kernel_launch(void* const* d_in, const int* in_sizes, int n_in,
                              void* d_out, int out_size, void* d_ws, size_t ws_size,
                              hipStream_t stream) {
    const float* x  = (const float*)d_in[0];
    const float* h0 = (const float*)d_in[1];
    const float* Wi = (const float*)d_in[2];
    const float* Wh = (const float*)d_in[3];
    const float* Wo = (const float*)d_in[4];
    float* out = (float*)d_out;
    rnn_kernel<<<dim3(BATCH / MT), dim3(512), 0, stream>>>(x, h0, Wi, Wh, Wo, out);
}

// Round 6
// 759.204 us; speedup vs baseline: 1.1768x; 1.1165x over previous
//
#include <hip/hip_runtime.h>
#include <hip/hip_bf16.h>

#define FRAMES 512
#define BATCH 2048
#define IN_DIM 84
#define HIDDEN 300
#define OUT_DIM 10

#define MT 16            // batch rows per workgroup
#define RSTR 512         // row stride in shorts (g(r,c) = r*512 + 8*(r&7) + c)
#define XCOL 320         // x column base within a row
#define BUFS (MT * RSTR) // shorts per buffer (16 KiB)
#define NT 3             // uniform tiles per wave: t = wv, wv+8, wv+16 (>=19 -> zero weights)

typedef __attribute__((ext_vector_type(8))) short s8v;
typedef __attribute__((ext_vector_type(4))) short s4v;
typedef __attribute__((ext_vector_type(4))) float f4v;

__device__ __forceinline__ short f2b(float x) {
    __hip_bfloat16 h = __float2bfloat16(x);
    return *reinterpret_cast<short*>(&h);
}
__device__ __forceinline__ float b2f(short s) {
    __hip_bfloat16 h = *reinterpret_cast<__hip_bfloat16*>(&s);
    return __bfloat162float(h);
}
__device__ __forceinline__ float fast_tanh(float z) {
    float ex = __builtin_amdgcn_exp2f(z * 2.88539008177792681f); // exp(2z)
    return fmaf(-2.f, __builtin_amdgcn_rcpf(ex + 1.f), 1.f);
}
__device__ __forceinline__ int g(int r, int c) {   // swizzled LDS index (shorts)
    return r * RSTR + ((r & 7) << 3) + c;
}

// Swapped-operand step:  D[n][b] = sum_k W[n][k] * h[b][k]
//   A = weight tile (registers/AGPR), B = h fragment (LDS b128), C/D: lane l
//   holds batch=l&15, 4 consecutive hidden cols -> one ds_write_b64 per tile.

__global__ __launch_bounds__(512, 2)
void rnn_kernel(const float* __restrict__ x, const float* __restrict__ h0,
                const float* __restrict__ Wi, const float* __restrict__ Wh,
                const float* __restrict__ Wo, float* __restrict__ out)
{
    __shared__ short lds[2 * BUFS];
    const int tid  = threadIdx.x;
    const int lane = tid & 63;
    const int wv   = tid >> 6;          // wave 0..7
    const int l15  = lane & 15;
    const int lkhi = lane >> 4;         // k-subchunk 0..3 / n_local quad
    const int b0   = blockIdx.x * MT;

    // ---- weight-stationary A-fragments; t>=19 naturally zero via n<HIDDEN ----
    s8v w[NT][13];
#pragma unroll
    for (int i = 0; i < NT; ++i) {
        const int n = (wv + 8 * i) * 16 + l15;
#pragma unroll
        for (int kf = 0; kf < 10; ++kf) {
            s8v v;
#pragma unroll
            for (int j = 0; j < 8; ++j) {
                int k = kf * 32 + lkhi * 8 + j;
                float f = (n < HIDDEN && k < HIDDEN) ? Wh[n * HIDDEN + k] : 0.f;
                v[j] = f2b(f);
            }
            w[i][kf] = v;
        }
#pragma unroll
        for (int kf = 10; kf < 13; ++kf) {
            s8v v;
#pragma unroll
            for (int j = 0; j < 8; ++j) {
                int k = (kf - 10) * 32 + lkhi * 8 + j;
                float f = (n < HIDDEN && k < IN_DIM) ? Wi[n * IN_DIM + k] : 0.f;
                v[j] = f2b(f);
            }
            w[i][kf] = v;
        }
    }

    // ---- zero both buffers (covers all pad/unused slots) ----
    {
        s4v z = (s4v){0, 0, 0, 0};
        for (int i = tid; i < 2 * BUFS / 4; i += 512)
            ((s4v*)lds)[i] = z;
    }
    __syncthreads();

    // ---- h0 -> buf0, frame-0 x -> buf0 ----
    for (int i = tid; i < MT * HIDDEN; i += 512) {
        int r = i / HIDDEN, c = i % HIDDEN;
        lds[g(r, c)] = f2b(h0[(size_t)(b0 + r) * HIDDEN + c]);
    }
    if (tid < 336) {
        const float4* xs = reinterpret_cast<const float4*>(x + (size_t)b0 * IN_DIM);
        float4 v0 = xs[tid];
        int r = tid / 21, c4 = (tid % 21) * 4;
        s4v pk = {f2b(v0.x), f2b(v0.y), f2b(v0.z), f2b(v0.w)};
        *reinterpret_cast<s4v*>(&lds[g(r, XCOL + c4)]) = pk;
    }
    __syncthreads();

    // ---- per-lane constant bases (shorts) ----
    const int rdh = g(l15, lkhi * 8);           // B-frag read base (h: +kf*32, x: +320+j*32)
    const int wrb = g(l15, lkhi * 4);           // h' write base (+t*16)
    const int xr  = tid / 21, xc4 = (tid % 21) * 4;
    const int xcb = g(xr, XCOL + xc4);          // x commit base
    const bool xact = (tid < 336);
    const bool w3   = (wv < 3);                 // third tile real (t = wv+16 < 19)

    // ---- main loop, 2-step unrolled: all LDS offsets compile-time ----
#define STEP(PH, SF)                                                            \
    {                                                                           \
        float4 xv;                                                              \
        const bool pf = ((SF) + 1 < FRAMES) && xact;                            \
        if (pf) {                                                               \
            const float4* xs = reinterpret_cast<const float4*>(                 \
                x + ((size_t)((SF) + 1) * BATCH + b0) * IN_DIM);                \
            xv = xs[tid];                                                       \
        }                                                                       \
        s8v bf[13];                                                             \
        _Pragma("unroll")                                                       \
        for (int kf = 0; kf < 10; ++kf)                                         \
            bf[kf] = *(const s8v*)&lds[(PH) * BUFS + rdh + kf * 32];            \
        _Pragma("unroll")                                                       \
        for (int j = 0; j < 3; ++j)                                             \
            bf[10 + j] = *(const s8v*)&lds[(PH) * BUFS + rdh + XCOL + j * 32];  \
        f4v acc[NT];                                                            \
        _Pragma("unroll")                                                       \
        for (int i = 0; i < NT; ++i) acc[i] = (f4v){0.f, 0.f, 0.f, 0.f};        \
        _Pragma("unroll")                                                       \
        for (int kf = 0; kf < 13; ++kf) {                                       \
            _Pragma("unroll")                                                   \
            for (int i = 0; i < NT; ++i)                                        \
                acc[i] = __builtin_amdgcn_mfma_f32_16x16x32_bf16(               \
                    w[i][kf], bf[kf], acc[i], 0, 0, 0);                         \
        }                                                                       \
        _Pragma("unroll")                                                       \
        for (int i = 0; i < 2; ++i) {                                           \
            s4v hv;                                                             \
            _Pragma("unroll")                                                   \
            for (int r = 0; r < 4; ++r) hv[r] = f2b(fast_tanh(acc[i][r]));      \
            *(s4v*)&lds[((PH) ^ 1) * BUFS + wrb + (wv + 8 * i) * 16] = hv;      \
        }                                                                       \
        if (w3) {                                                               \
            s4v hv;                                                             \
            _Pragma("unroll")                                                   \
            for (int r = 0; r < 4; ++r) hv[r] = f2b(fast_tanh(acc[2][r]));      \
            *(s4v*)&lds[((PH) ^ 1) * BUFS + wrb + (wv + 16) * 16] = hv;         \
        }                                                                       \
        if (pf) {                                                               \
            s4v pk = {f2b(xv.x), f2b(xv.y), f2b(xv.z), f2b(xv.w)};              \
            *(s4v*)&lds[((PH) ^ 1) * BUFS + xcb] = pk;                          \
        }                                                                       \
        __syncthreads();                                                        \
    }

    for (int s = 0; s < FRAMES; s += 2) {
        STEP(0, s)
        STEP(1, s + 1)
    }
#undef STEP

    // ---- epilogue: final h in buf0 (FRAMES even) ----
    float* hout = out + BATCH * OUT_DIM;
    for (int i = tid; i < MT * HIDDEN; i += 512) {
        int r = i / HIDDEN, c = i % HIDDEN;
        hout[(size_t)(b0 + r) * HIDDEN + c] = b2f(lds[g(r, c)]);
    }
    if (tid < MT * OUT_DIM) {
        int r = tid / OUT_DIM, c = tid % OUT_DIM;
        float sum = 0.f;
        for (int k = 0; k < HIDDEN; ++k)
            sum = fmaf(b2f(lds[g(r, k)]), Wo[c * HIDDEN + k], sum);
        out[(b0 + r) * OUT_DIM + c] = sum;
    }
}

extern "C" void kernel_launch(void* const* d_in, const int* in_sizes, int n_in,
                              void* d_out, int out_size, void* d_ws, size_t ws_size,
                              hipStream_t stream) {
    const float* x  = (const float*)d_in[0];
    const float* h0 = (const float*)d_in[1];
    const float* Wi = (const float*)d_in[2];
    const float* Wh = (const float*)d_in[3];
    const float* Wo = (const float*)d_in[4];
    float* out = (float*)d_out;
    rnn_kernel<<<dim3(BATCH / MT), dim3(512), 0, stream>>>(x, h0, Wi, Wh, Wo, out);
}